// Round 1
// baseline (893.226 us; speedup 1.0000x reference)
//
#include <hip/hip_runtime.h>

// Problem: B=8, C=512, N=2048, P=256.
// Pipeline (all fp32):
//   g,theta,phi = W @ x_b          (3x GEMM NN, M=256 K=512 N=2048, per batch)
//   f = theta^T @ phi              (GEMM TN, M=2048 K=256 N=2048)
//   softmax rows of f
//   y = g @ f^T                    (GEMM NT, M=256 K=2048 N=2048)
//   z = Wz @ y                     (GEMM NN, M=512 K=256 N=2048)
//   BN over (b,n) per channel, *gamma+beta, +x residual
//
// Workspace (floats): g[4M] | theta[4M] | phi[4M] | f[33.5M]
//   y aliases theta (dead after f), z aliases f (dead after y),
//   mean/rstd alias phi (dead after f). Total = 176 MB.

#define TM 64
#define TN 64
#define TK 16
#define PAD 4   // keeps 16B alignment for float4 LDS reads (row stride 68 floats)

template <bool TRANSA, bool TRANSB>
__global__ __launch_bounds__(256) void gemm_tiled(
    const float* __restrict__ A, const float* __restrict__ B,
    float* __restrict__ C, int M, int N, int K, int lda, int ldb, int ldc,
    long strideA, long strideB, long strideC)
{
    A += (long)blockIdx.z * strideA;
    B += (long)blockIdx.z * strideB;
    C += (long)blockIdx.z * strideC;

    __shared__ float As[TK][TM + PAD];
    __shared__ float Bs[TK][TN + PAD];

    const int tid = threadIdx.x;        // 0..255
    const int tx = tid & 15;            // 0..15
    const int ty = tid >> 4;            // 0..15
    const int m0 = blockIdx.y * TM;
    const int n0 = blockIdx.x * TN;

    float acc[4][4] = {};

    for (int k0 = 0; k0 < K; k0 += TK) {
        // ---- load A tile: As[k][m] = A(m0+m, k0+k) ----
        if (TRANSA) {
            // A(m,k) = A[k*lda + m] — coalesced along m
            const int m = tid & 63;
            const int kb = tid >> 6;    // 0..3
#pragma unroll
            for (int i = 0; i < 4; ++i) {
                const int k = kb + i * 4;
                As[k][m] = A[(long)(k0 + k) * lda + (m0 + m)];
            }
        } else {
            // A(m,k) = A[m*lda + k] — coalesced along k
            const int k = tid & 15;
            const int mb = tid >> 4;    // 0..15
#pragma unroll
            for (int i = 0; i < 4; ++i) {
                const int m = mb + i * 16;
                As[k][m] = A[(long)(m0 + m) * lda + (k0 + k)];
            }
        }
        // ---- load B tile: Bs[k][n] = B(k0+k, n0+n) ----
        if (TRANSB) {
            // B(k,n) = B[n*ldb + k] — coalesced along k
            const int k = tid & 15;
            const int nb = tid >> 4;
#pragma unroll
            for (int i = 0; i < 4; ++i) {
                const int n = nb + i * 16;
                Bs[k][n] = B[(long)(n0 + n) * ldb + (k0 + k)];
            }
        } else {
            // B(k,n) = B[k*ldb + n] — coalesced along n
            const int n = tid & 63;
            const int kb = tid >> 6;
#pragma unroll
            for (int i = 0; i < 4; ++i) {
                const int k = kb + i * 4;
                Bs[k][n] = B[(long)(k0 + k) * ldb + (n0 + n)];
            }
        }
        __syncthreads();

#pragma unroll
        for (int k = 0; k < TK; ++k) {
            const float4 a4 = *(const float4*)&As[k][ty * 4];
            const float4 b4 = *(const float4*)&Bs[k][tx * 4];
            const float a[4] = {a4.x, a4.y, a4.z, a4.w};
            const float b[4] = {b4.x, b4.y, b4.z, b4.w};
#pragma unroll
            for (int i = 0; i < 4; ++i)
#pragma unroll
                for (int j = 0; j < 4; ++j) acc[i][j] += a[i] * b[j];
        }
        __syncthreads();
    }

#pragma unroll
    for (int i = 0; i < 4; ++i) {
        const int m = m0 + ty * 4 + i;
        float4 st = {acc[i][0], acc[i][1], acc[i][2], acc[i][3]};
        *(float4*)&C[(long)m * ldc + n0 + tx * 4] = st;
    }
}

__global__ __launch_bounds__(256) void softmax_rows(float* __restrict__ f, int N)
{
    float* p = f + (long)blockIdx.x * N;
    const int tid = threadIdx.x;
    float v[8];
    float mx = -1e30f;
#pragma unroll
    for (int i = 0; i < 8; ++i) {
        v[i] = p[tid + i * 256];
        mx = fmaxf(mx, v[i]);
    }
    __shared__ float red[256];
    red[tid] = mx;
    __syncthreads();
    for (int s = 128; s > 0; s >>= 1) {
        if (tid < s) red[tid] = fmaxf(red[tid], red[tid + s]);
        __syncthreads();
    }
    mx = red[0];
    __syncthreads();
    float sum = 0.f;
#pragma unroll
    for (int i = 0; i < 8; ++i) {
        v[i] = __expf(v[i] - mx);
        sum += v[i];
    }
    red[tid] = sum;
    __syncthreads();
    for (int s = 128; s > 0; s >>= 1) {
        if (tid < s) red[tid] += red[tid + s];
        __syncthreads();
    }
    const float inv = 1.0f / red[0];
#pragma unroll
    for (int i = 0; i < 8; ++i) p[tid + i * 256] = v[i] * inv;
}

__global__ __launch_bounds__(256) void bn_stats(
    const float* __restrict__ z, float* __restrict__ mean, float* __restrict__ rstd,
    int B, int C, int N)
{
    const int c = blockIdx.x;
    const int tid = threadIdx.x;
    float s = 0.f, sq = 0.f;
    for (int b = 0; b < B; ++b) {
        const float* p = z + ((long)b * C + c) * N;
        for (int i = tid; i < N; i += 256) {
            const float v = p[i];
            s += v;
            sq += v * v;
        }
    }
    __shared__ float rs[256], rq[256];
    rs[tid] = s;
    rq[tid] = sq;
    __syncthreads();
    for (int st = 128; st > 0; st >>= 1) {
        if (tid < st) { rs[tid] += rs[tid + st]; rq[tid] += rq[tid + st]; }
        __syncthreads();
    }
    if (tid == 0) {
        const float cnt = (float)B * (float)N;
        const float m = rs[0] / cnt;
        const float var = rq[0] / cnt - m * m;
        mean[c] = m;
        rstd[c] = rsqrtf(var + 1e-5f);
    }
}

__global__ __launch_bounds__(256) void bn_apply(
    const float* __restrict__ z, const float* __restrict__ x,
    const float* __restrict__ mean, const float* __restrict__ rstd,
    const float* __restrict__ gamma, const float* __restrict__ beta,
    float* __restrict__ out, int C, int N)
{
    const long i = (long)blockIdx.x * 256 + threadIdx.x;
    const int c = (int)((i / N) % C);
    out[i] = (z[i] - mean[c]) * rstd[c] * gamma[c] + beta[c] + x[i];
}

extern "C" void kernel_launch(void* const* d_in, const int* in_sizes, int n_in,
                              void* d_out, int out_size, void* d_ws, size_t ws_size,
                              hipStream_t stream)
{
    const int B = 8, C = 512, N = 2048, P = 256;
    const float* x      = (const float*)d_in[0];
    const float* Wg     = (const float*)d_in[1];
    const float* Wtheta = (const float*)d_in[2];
    const float* Wphi   = (const float*)d_in[3];
    const float* Wz     = (const float*)d_in[4];
    const float* gamma  = (const float*)d_in[5];
    const float* beta   = (const float*)d_in[6];
    float* out = (float*)d_out;

    float* ws = (float*)d_ws;
    const long PN = (long)B * P * N;          // 4194304 per tensor
    float* g     = ws;                        // [B,P,N]
    float* theta = ws + PN;                   // [B,P,N]
    float* phi   = ws + 2 * PN;               // [B,P,N]
    float* f     = ws + 3 * PN;               // [B,N,N] = 33554432 floats
    float* y     = theta;                     // reuse (theta dead after f)
    float* z     = f;                         // reuse (f dead after y)
    float* mean  = phi;                       // reuse (phi dead after f)
    float* rstd  = phi + 512;

    const long sX = (long)C * N;              // x batch stride
    const long sP = (long)P * N;              // g/theta/phi/y batch stride
    const long sF = (long)N * N;              // f batch stride
    const long sZ = (long)C * N;              // z batch stride

    // projections: W (PxC, rm) @ x_b (CxN, rm) -> (PxN)
    dim3 gproj(N / TN, P / TM, B);
    gemm_tiled<false, false><<<gproj, 256, 0, stream>>>(Wg, x, g, P, N, C, C, N, N, 0, sX, sP);
    gemm_tiled<false, false><<<gproj, 256, 0, stream>>>(Wtheta, x, theta, P, N, C, C, N, N, 0, sX, sP);
    gemm_tiled<false, false><<<gproj, 256, 0, stream>>>(Wphi, x, phi, P, N, C, C, N, N, 0, sX, sP);

    // scores: f[n,m] = sum_p theta[p,n] * phi[p,m]  (A^T B)
    dim3 gsc(N / TN, N / TM, B);
    gemm_tiled<true, false><<<gsc, 256, 0, stream>>>(theta, phi, f, N, N, P, N, N, N, sP, sP, sF);

    // row softmax over m
    softmax_rows<<<B * N, 256, 0, stream>>>(f, N);

    // y[p,n] = sum_m g[p,m] * f[n,m]  (A B^T)
    dim3 gy(N / TN, P / TM, B);
    gemm_tiled<false, true><<<gy, 256, 0, stream>>>(g, f, y, P, N, N, N, N, N, sP, sF, sP);

    // z = Wz (CxP, rm) @ y (PxN)
    dim3 gz(N / TN, C / TM, B);
    gemm_tiled<false, false><<<gz, 256, 0, stream>>>(Wz, y, z, C, N, P, P, N, N, 0, sP, sZ);

    // BatchNorm stats + apply + residual
    bn_stats<<<C, 256, 0, stream>>>(z, mean, rstd, B, C, N);
    bn_apply<<<(B * (long)C * N) / 256, 256, 0, stream>>>(z, x, mean, rstd, gamma, beta, out, C, N);
}

// Round 2
// 583.759 us; speedup vs baseline: 1.5301x; 1.5301x over previous
//
#include <hip/hip_runtime.h>
#include <hip/hip_bf16.h>

// B=8, C=512, N=2048, P=256.
// Round 2: MFMA (bf16 16x16x32) for the two attention GEMMs.
//   scores: split-bf16 (hi/lo, 3 MFMAs) -> fp32-class logit accuracy
//   y:      plain bf16 (post-softmax errors are not exp-amplified)
// Projections + z stay on the fp32 VALU GEMM (next round: MFMA those too).
//
// Workspace (floats, total 39.84M = 159.4 MB):
//   buf1 4.19M | thetaT_hi 2.10 | thetaT_lo 2.10 | phiT_hi 2.10 | phiT_lo 2.10
//   | g_bf 2.10 | f32chunk 8.39 | f_bf 16.78
// f is processed in 4 chunks of 512 rows (fp32 logits never fully materialize).

#define TM 64
#define TN 64
#define TK 16
#define PAD 4

// ---------------- fp32 VALU GEMM (projections, z) ----------------
template <bool TRANSA, bool TRANSB>
__global__ __launch_bounds__(256) void gemm_tiled(
    const float* __restrict__ A, const float* __restrict__ B,
    float* __restrict__ C, int M, int N, int K, int lda, int ldb, int ldc,
    long strideA, long strideB, long strideC)
{
    A += (long)blockIdx.z * strideA;
    B += (long)blockIdx.z * strideB;
    C += (long)blockIdx.z * strideC;

    __shared__ float As[TK][TM + PAD];
    __shared__ float Bs[TK][TN + PAD];

    const int tid = threadIdx.x;
    const int tx = tid & 15;
    const int ty = tid >> 4;
    const int m0 = blockIdx.y * TM;
    const int n0 = blockIdx.x * TN;

    float acc[4][4] = {};

    for (int k0 = 0; k0 < K; k0 += TK) {
        if (TRANSA) {
            const int m = tid & 63;
            const int kb = tid >> 6;
#pragma unroll
            for (int i = 0; i < 4; ++i) {
                const int k = kb + i * 4;
                As[k][m] = A[(long)(k0 + k) * lda + (m0 + m)];
            }
        } else {
            const int k = tid & 15;
            const int mb = tid >> 4;
#pragma unroll
            for (int i = 0; i < 4; ++i) {
                const int m = mb + i * 16;
                As[k][m] = A[(long)(m0 + m) * lda + (k0 + k)];
            }
        }
        if (TRANSB) {
            const int k = tid & 15;
            const int nb = tid >> 4;
#pragma unroll
            for (int i = 0; i < 4; ++i) {
                const int n = nb + i * 16;
                Bs[k][n] = B[(long)(n0 + n) * ldb + (k0 + k)];
            }
        } else {
            const int n = tid & 63;
            const int kb = tid >> 6;
#pragma unroll
            for (int i = 0; i < 4; ++i) {
                const int k = kb + i * 4;
                Bs[k][n] = B[(long)(k0 + k) * ldb + (n0 + n)];
            }
        }
        __syncthreads();

#pragma unroll
        for (int k = 0; k < TK; ++k) {
            const float4 a4 = *(const float4*)&As[k][ty * 4];
            const float4 b4 = *(const float4*)&Bs[k][tx * 4];
            const float a[4] = {a4.x, a4.y, a4.z, a4.w};
            const float b[4] = {b4.x, b4.y, b4.z, b4.w};
#pragma unroll
            for (int i = 0; i < 4; ++i)
#pragma unroll
                for (int j = 0; j < 4; ++j) acc[i][j] += a[i] * b[j];
        }
        __syncthreads();
    }

#pragma unroll
    for (int i = 0; i < 4; ++i) {
        const int m = m0 + ty * 4 + i;
        float4 st = {acc[i][0], acc[i][1], acc[i][2], acc[i][3]};
        *(float4*)&C[(long)m * ldc + n0 + tx * 4] = st;
    }
}

// ---------------- bf16 helpers ----------------
__device__ __forceinline__ unsigned short f2bf(float v) {
    __hip_bfloat16 h = __float2bfloat16(v);
    return *(unsigned short*)&h;
}
__device__ __forceinline__ float bf2f(unsigned short u) {
    __hip_bfloat16 h;
    *(unsigned short*)&h = u;
    return __bfloat162float(h);
}

// transpose + hi/lo split: X [P][N] fp32 -> Thi/Tlo [N][P] bf16 (batched)
__global__ __launch_bounds__(256) void transpose_split(
    const float* __restrict__ X, unsigned short* __restrict__ Thi,
    unsigned short* __restrict__ Tlo, int P, int N)
{
    X   += (long)blockIdx.z * P * N;
    Thi += (long)blockIdx.z * N * P;
    Tlo += (long)blockIdx.z * N * P;
    __shared__ float s[32][33];
    const int tx = threadIdx.x & 31, ty = threadIdx.x >> 5;   // ty 0..7
    const int n0 = blockIdx.x * 32, p0 = blockIdx.y * 32;
#pragma unroll
    for (int r = 0; r < 4; ++r)
        s[ty + r * 8][tx] = X[(long)(p0 + ty + r * 8) * N + n0 + tx];
    __syncthreads();
#pragma unroll
    for (int r = 0; r < 4; ++r) {
        const int n = ty + r * 8;
        const float v = s[tx][n];
        const unsigned short hi = f2bf(v);
        const unsigned short lo = f2bf(v - bf2f(hi));
        Thi[(long)(n0 + n) * P + p0 + tx] = hi;
        Tlo[(long)(n0 + n) * P + p0 + tx] = lo;
    }
}

// elementwise fp32 -> bf16 (vector-4)
__global__ __launch_bounds__(256) void cast_bf16(
    const float* __restrict__ X, unsigned short* __restrict__ Y)
{
    const long i = ((long)blockIdx.x * 256 + threadIdx.x) * 4;
    const float4 v = *(const float4*)&X[i];
    ushort4 o;
    o.x = f2bf(v.x); o.y = f2bf(v.y); o.z = f2bf(v.z); o.w = f2bf(v.w);
    *(ushort4*)&Y[i] = o;
}

// ---------------- MFMA GEMM ----------------
// C[M][N] (fp32) = A[M][K] * B[N][K]^T, A/B bf16 row-major with K contiguous.
// SPLIT: C = Ah*Bh + Ah*Bl + Al*Bh (near-fp32 accuracy).
typedef __attribute__((ext_vector_type(8))) short short8;
typedef __attribute__((ext_vector_type(4))) float floatx4;

#define MT 128
#define BK 32
#define LDK 40   // padded LDS k-stride (ushorts): 80B rows -> conflict-free-ish

template <bool SPLIT>
__global__ __launch_bounds__(256) void mfma_gemm(
    const unsigned short* __restrict__ Ahi, const unsigned short* __restrict__ Alo,
    const unsigned short* __restrict__ Bhi, const unsigned short* __restrict__ Blo,
    float* __restrict__ C,
    int M, int N, int K, int lda, int ldb, int ldc,
    long sA, long sB, long sC)
{
    Ahi += (long)blockIdx.z * sA;
    Bhi += (long)blockIdx.z * sB;
    if (SPLIT) { Alo += (long)blockIdx.z * sA; Blo += (long)blockIdx.z * sB; }
    C += (long)blockIdx.z * sC;

    __shared__ unsigned short AsH[MT * LDK], BsH[MT * LDK];
    __shared__ unsigned short AsL[SPLIT ? MT * LDK : 8], BsL[SPLIT ? MT * LDK : 8];

    const int tid = threadIdx.x;
    const int wid = tid >> 6, lane = tid & 63;
    const int wm = (wid >> 1) * 64, wn = (wid & 1) * 64;
    const int l15 = lane & 15, quad = lane >> 4;
    const int m0 = blockIdx.y * MT, n0 = blockIdx.x * MT;

    const int srow = tid >> 1, scol = (tid & 1) * 16;   // staging: 16 bf16/thread/array

    floatx4 acc[4][4];
#pragma unroll
    for (int i = 0; i < 4; ++i)
#pragma unroll
        for (int j = 0; j < 4; ++j) acc[i][j] = (floatx4){0.f, 0.f, 0.f, 0.f};

    const long arow = (long)(m0 + srow) * lda + scol;
    const long brow = (long)(n0 + srow) * ldb + scol;

    for (int k0 = 0; k0 < K; k0 += BK) {
        // stage tiles (each thread: 2x16B per array)
        {
            const unsigned short* ga = Ahi + arow + k0;
            const unsigned short* gb = Bhi + brow + k0;
            *(float4*)&AsH[srow * LDK + scol]     = *(const float4*)&ga[0];
            *(float4*)&AsH[srow * LDK + scol + 8] = *(const float4*)&ga[8];
            *(float4*)&BsH[srow * LDK + scol]     = *(const float4*)&gb[0];
            *(float4*)&BsH[srow * LDK + scol + 8] = *(const float4*)&gb[8];
            if (SPLIT) {
                const unsigned short* la = Alo + arow + k0;
                const unsigned short* lb = Blo + brow + k0;
                *(float4*)&AsL[srow * LDK + scol]     = *(const float4*)&la[0];
                *(float4*)&AsL[srow * LDK + scol + 8] = *(const float4*)&la[8];
                *(float4*)&BsL[srow * LDK + scol]     = *(const float4*)&lb[0];
                *(float4*)&BsL[srow * LDK + scol + 8] = *(const float4*)&lb[8];
            }
        }
        __syncthreads();

        short8 ah[4], bh[4], al[4], bl[4];
#pragma unroll
        for (int i = 0; i < 4; ++i) {
            ah[i] = *(const short8*)&AsH[(wm + i * 16 + l15) * LDK + quad * 8];
            bh[i] = *(const short8*)&BsH[(wn + i * 16 + l15) * LDK + quad * 8];
            if (SPLIT) {
                al[i] = *(const short8*)&AsL[(wm + i * 16 + l15) * LDK + quad * 8];
                bl[i] = *(const short8*)&BsL[(wn + i * 16 + l15) * LDK + quad * 8];
            }
        }
#pragma unroll
        for (int i = 0; i < 4; ++i)
#pragma unroll
            for (int j = 0; j < 4; ++j) {
                acc[i][j] = __builtin_amdgcn_mfma_f32_16x16x32_bf16(ah[i], bh[j], acc[i][j], 0, 0, 0);
                if (SPLIT) {
                    acc[i][j] = __builtin_amdgcn_mfma_f32_16x16x32_bf16(ah[i], bl[j], acc[i][j], 0, 0, 0);
                    acc[i][j] = __builtin_amdgcn_mfma_f32_16x16x32_bf16(al[i], bh[j], acc[i][j], 0, 0, 0);
                }
            }
        __syncthreads();
    }

    // C/D layout: col = lane&15, row = quad*4 + reg
#pragma unroll
    for (int i = 0; i < 4; ++i)
#pragma unroll
        for (int j = 0; j < 4; ++j) {
            const int m = m0 + wm + i * 16 + quad * 4;
            const int n = n0 + wn + j * 16 + l15;
#pragma unroll
            for (int r = 0; r < 4; ++r)
                C[(long)(m + r) * ldc + n] = acc[i][j][r];
        }
}

// ---------------- softmax: fp32 chunk row -> bf16 full-f row ----------------
__global__ __launch_bounds__(256) void softmax_bf(
    const float* __restrict__ fin, unsigned short* __restrict__ fout,
    int N, int rowsPerBatch, int noff)
{
    const int b = blockIdx.x / rowsPerBatch;
    const int nc = blockIdx.x % rowsPerBatch;
    const float* p = fin + (long)blockIdx.x * N;
    unsigned short* q = fout + ((long)b * N + noff + nc) * N;
    const int tid = threadIdx.x;
    float v[8];
    float mx = -1e30f;
#pragma unroll
    for (int i = 0; i < 8; ++i) {
        v[i] = p[tid + i * 256];
        mx = fmaxf(mx, v[i]);
    }
    __shared__ float red[256];
    red[tid] = mx;
    __syncthreads();
    for (int s = 128; s > 0; s >>= 1) {
        if (tid < s) red[tid] = fmaxf(red[tid], red[tid + s]);
        __syncthreads();
    }
    mx = red[0];
    __syncthreads();
    float sum = 0.f;
#pragma unroll
    for (int i = 0; i < 8; ++i) {
        v[i] = __expf(v[i] - mx);
        sum += v[i];
    }
    red[tid] = sum;
    __syncthreads();
    for (int s = 128; s > 0; s >>= 1) {
        if (tid < s) red[tid] += red[tid + s];
        __syncthreads();
    }
    const float inv = 1.0f / red[0];
#pragma unroll
    for (int i = 0; i < 8; ++i) q[tid + i * 256] = f2bf(v[i] * inv);
}

// ---------------- BatchNorm ----------------
__global__ __launch_bounds__(256) void bn_stats(
    const float* __restrict__ z, float* __restrict__ mean, float* __restrict__ rstd,
    int B, int C, int N)
{
    const int c = blockIdx.x;
    const int tid = threadIdx.x;
    float s = 0.f, sq = 0.f;
    for (int b = 0; b < B; ++b) {
        const float* p = z + ((long)b * C + c) * N;
        for (int i = tid; i < N; i += 256) {
            const float v = p[i];
            s += v;
            sq += v * v;
        }
    }
    __shared__ float rs[256], rq[256];
    rs[tid] = s;
    rq[tid] = sq;
    __syncthreads();
    for (int st = 128; st > 0; st >>= 1) {
        if (tid < st) { rs[tid] += rs[tid + st]; rq[tid] += rq[tid + st]; }
        __syncthreads();
    }
    if (tid == 0) {
        const float cnt = (float)B * (float)N;
        const float m = rs[0] / cnt;
        const float var = rq[0] / cnt - m * m;
        mean[c] = m;
        rstd[c] = rsqrtf(var + 1e-5f);
    }
}

__global__ __launch_bounds__(256) void bn_apply(
    const float* __restrict__ z, const float* __restrict__ x,
    const float* __restrict__ mean, const float* __restrict__ rstd,
    const float* __restrict__ gamma, const float* __restrict__ beta,
    float* __restrict__ out, int C, int N)
{
    const long i = (long)blockIdx.x * 256 + threadIdx.x;
    const int c = (int)((i / N) % C);
    out[i] = (z[i] - mean[c]) * rstd[c] * gamma[c] + beta[c] + x[i];
}

extern "C" void kernel_launch(void* const* d_in, const int* in_sizes, int n_in,
                              void* d_out, int out_size, void* d_ws, size_t ws_size,
                              hipStream_t stream)
{
    const int B = 8, C = 512, N = 2048, P = 256;
    const int NC = 512;                     // f row-chunk
    const float* x      = (const float*)d_in[0];
    const float* Wg     = (const float*)d_in[1];
    const float* Wtheta = (const float*)d_in[2];
    const float* Wphi   = (const float*)d_in[3];
    const float* Wz     = (const float*)d_in[4];
    const float* gamma  = (const float*)d_in[5];
    const float* beta   = (const float*)d_in[6];
    float* out = (float*)d_out;

    // ---- workspace layout (float units) ----
    float* ws = (float*)d_ws;
    const long PN = (long)B * P * N;        // 4,194,304
    float*          buf1  = ws;                              // 4.19M fp32
    unsigned short* thH   = (unsigned short*)(ws + PN);      // B*N*P bf16
    unsigned short* thL   = (unsigned short*)(ws + PN + PN / 2);
    unsigned short* phH   = (unsigned short*)(ws + 2 * PN);
    unsigned short* phL   = (unsigned short*)(ws + 2 * PN + PN / 2);
    unsigned short* gbf   = (unsigned short*)(ws + 3 * PN);  // B*P*N bf16
    float*          f32c  = ws + 3 * PN + PN / 2;            // B*NC*N fp32 = 8.39M
    unsigned short* fbf   = (unsigned short*)(ws + 3 * PN + PN / 2 + (long)B * NC * N);
    float*          mean  = (float*)thH;                     // dead after scores
    float*          rstd  = mean + C;
    float*          y     = buf1;                            // reuse
    float*          z     = f32c;                            // reuse

    const long sX = (long)C * N;
    const long sP = (long)P * N;            // 524288, also = N*P

    // 1-6: projections (fp32) + split/cast
    dim3 gproj(N / TN, P / TM, B);
    dim3 gtr(N / 32, P / 32, B);
    gemm_tiled<false, false><<<gproj, 256, 0, stream>>>(Wtheta, x, buf1, P, N, C, C, N, N, 0, sX, sP);
    transpose_split<<<gtr, 256, 0, stream>>>(buf1, thH, thL, P, N);
    gemm_tiled<false, false><<<gproj, 256, 0, stream>>>(Wphi, x, buf1, P, N, C, C, N, N, 0, sX, sP);
    transpose_split<<<gtr, 256, 0, stream>>>(buf1, phH, phL, P, N);
    gemm_tiled<false, false><<<gproj, 256, 0, stream>>>(Wg, x, buf1, P, N, C, C, N, N, 0, sX, sP);
    cast_bf16<<<(int)(B * sP / 1024), 256, 0, stream>>>(buf1, gbf);

    // 7: scores (split MFMA) + softmax, chunked over n rows
    for (int c = 0; c < N / NC; ++c) {
        dim3 gsc(N / MT, NC / MT, B);
        mfma_gemm<true><<<gsc, 256, 0, stream>>>(
            thH + (long)c * NC * P, thL + (long)c * NC * P, phH, phL, f32c,
            NC, N, P, P, P, N, (long)N * P, (long)N * P, (long)NC * N);
        softmax_bf<<<B * NC, 256, 0, stream>>>(f32c, fbf, N, NC, c * NC);
    }

    // 8: y = g @ f^T (plain bf16 MFMA): M=P, N=N, K=N
    {
        dim3 gy(N / MT, P / MT, B);
        mfma_gemm<false><<<gy, 256, 0, stream>>>(
            gbf, gbf, fbf, fbf, y,
            P, N, N, N, N, N, sP, (long)N * N, sP);
    }

    // 9: z = Wz @ y (fp32)
    dim3 gz(N / TN, C / TM, B);
    gemm_tiled<false, false><<<gz, 256, 0, stream>>>(Wz, y, z, C, N, P, P, N, N, 0, sP, sX);

    // 10-11: BN + residual
    bn_stats<<<C, 256, 0, stream>>>(z, mean, rstd, B, C, N);
    bn_apply<<<(int)((B * sX) / 256), 256, 0, stream>>>(z, x, mean, rstd, gamma, beta, out, C, N);
}

// Round 3
// 398.566 us; speedup vs baseline: 2.2411x; 1.4646x over previous
//
#include <hip/hip_runtime.h>
#include <hip/hip_bf16.h>

// B=8, C=512, N=2048, P=256.
// Round 3: ALL GEMMs on MFMA bf16 16x16x32.
//   theta/phi: split-bf16 (hi/lo, 3 MFMAs) end-to-end -> fp32-class logits
//   g, y, z:   plain bf16 (post-softmax, not exp-amplified)
// Layouts chosen so every GEMM operand is K-contiguous:
//   xT[h/l] = transpose+split of x       [B][N][C]
//   thT = xT @ Wth^T (split, split-out)  [B][N][P]
//   phT = xT @ Wph^T (split, split-out)  [B][N][P]
//   g   = Wg @ xT^T  (plain, bf16-out)   [B][P][N]
//   f   = thT @ phT^T (split, chunked) -> softmax -> fbf [B][N][N] bf16
//   yT  = fbf @ g^T  (plain, bf16-out)   [B][N][P]
//   z   = Wz @ yT^T  (plain, fp32-out)   [B][C][N]
//   BN(z)*gamma+beta + x -> out
// Workspace: 38.2M floats = 152.6 MB (<= 159 MB proven in round 2).

typedef __attribute__((ext_vector_type(8))) short short8;
typedef __attribute__((ext_vector_type(4))) float floatx4;

// ---------------- bf16 helpers ----------------
__device__ __forceinline__ unsigned short f2bf(float v) {
    __hip_bfloat16 h = __float2bfloat16(v);
    return *(unsigned short*)&h;
}
__device__ __forceinline__ float bf2f(unsigned short u) {
    __hip_bfloat16 h;
    *(unsigned short*)&h = u;
    return __bfloat162float(h);
}

// transpose + hi/lo split: X [R][N] fp32 -> Thi/Tlo [N][R] bf16 (batched over z)
__global__ __launch_bounds__(256) void transpose_split(
    const float* __restrict__ X, unsigned short* __restrict__ Thi,
    unsigned short* __restrict__ Tlo, int R, int N)
{
    X   += (long)blockIdx.z * R * N;
    Thi += (long)blockIdx.z * N * R;
    Tlo += (long)blockIdx.z * N * R;
    __shared__ float s[32][33];
    const int tx = threadIdx.x & 31, ty = threadIdx.x >> 5;   // ty 0..7
    const int n0 = blockIdx.x * 32, r0 = blockIdx.y * 32;
#pragma unroll
    for (int r = 0; r < 4; ++r)
        s[ty + r * 8][tx] = X[(long)(r0 + ty + r * 8) * N + n0 + tx];
    __syncthreads();
#pragma unroll
    for (int r = 0; r < 4; ++r) {
        const int n = ty + r * 8;
        const float v = s[tx][n];
        const unsigned short hi = f2bf(v);
        const unsigned short lo = f2bf(v - bf2f(hi));
        Thi[(long)(n0 + n) * R + r0 + tx] = hi;
        Tlo[(long)(n0 + n) * R + r0 + tx] = lo;
    }
}

// elementwise fp32 -> hi/lo bf16
__global__ __launch_bounds__(256) void split_w(
    const float* __restrict__ W, unsigned short* __restrict__ Whi,
    unsigned short* __restrict__ Wlo, int n)
{
    const int i = blockIdx.x * 256 + threadIdx.x;
    if (i < n) {
        const float v = W[i];
        const unsigned short hi = f2bf(v);
        Whi[i] = hi;
        Wlo[i] = f2bf(v - bf2f(hi));
    }
}

// elementwise fp32 -> bf16 (vector-4)
__global__ __launch_bounds__(256) void cast_bf16(
    const float* __restrict__ X, unsigned short* __restrict__ Y)
{
    const long i = ((long)blockIdx.x * 256 + threadIdx.x) * 4;
    const float4 v = *(const float4*)&X[i];
    ushort4 o;
    o.x = f2bf(v.x); o.y = f2bf(v.y); o.z = f2bf(v.z); o.w = f2bf(v.w);
    *(ushort4*)&Y[i] = o;
}

// ---------------- MFMA GEMM ----------------
// C[M][N] = A[M][K] * B[N][K]^T, bf16 inputs (K contiguous), fp32 accumulate.
// SPLIT: C = Ah*Bh + Ah*Bl + Al*Bh.
// OUTMODE: 0 = fp32 store, 1 = bf16 store, 2 = hi/lo bf16 split store.
#define MT 128
#define BK 32
#define LDK 40

template <bool SPLIT, int OUTMODE>
__global__ __launch_bounds__(256) void mfma_gemm(
    const unsigned short* __restrict__ Ahi, const unsigned short* __restrict__ Alo,
    const unsigned short* __restrict__ Bhi, const unsigned short* __restrict__ Blo,
    void* __restrict__ Cout, void* __restrict__ Cout2,
    int M, int N, int K, int lda, int ldb, int ldc,
    long sA, long sB, long sC)
{
    Ahi += (long)blockIdx.z * sA;
    Bhi += (long)blockIdx.z * sB;
    if (SPLIT) { Alo += (long)blockIdx.z * sA; Blo += (long)blockIdx.z * sB; }
    float* Cf = (float*)Cout + (long)blockIdx.z * sC;
    unsigned short* Ch = (unsigned short*)Cout + (long)blockIdx.z * sC;
    unsigned short* Cl = (unsigned short*)Cout2 + (long)blockIdx.z * sC;

    __shared__ unsigned short AsH[MT * LDK], BsH[MT * LDK];
    __shared__ unsigned short AsL[SPLIT ? MT * LDK : 8], BsL[SPLIT ? MT * LDK : 8];

    const int tid = threadIdx.x;
    const int wid = tid >> 6, lane = tid & 63;
    const int wm = (wid >> 1) * 64, wn = (wid & 1) * 64;
    const int l15 = lane & 15, quad = lane >> 4;
    const int m0 = blockIdx.y * MT, n0 = blockIdx.x * MT;

    const int srow = tid >> 1, scol = (tid & 1) * 16;

    floatx4 acc[4][4];
#pragma unroll
    for (int i = 0; i < 4; ++i)
#pragma unroll
        for (int j = 0; j < 4; ++j) acc[i][j] = (floatx4){0.f, 0.f, 0.f, 0.f};

    const long arow = (long)(m0 + srow) * lda + scol;
    const long brow = (long)(n0 + srow) * ldb + scol;

    for (int k0 = 0; k0 < K; k0 += BK) {
        {
            const unsigned short* ga = Ahi + arow + k0;
            const unsigned short* gb = Bhi + brow + k0;
            *(float4*)&AsH[srow * LDK + scol]     = *(const float4*)&ga[0];
            *(float4*)&AsH[srow * LDK + scol + 8] = *(const float4*)&ga[8];
            *(float4*)&BsH[srow * LDK + scol]     = *(const float4*)&gb[0];
            *(float4*)&BsH[srow * LDK + scol + 8] = *(const float4*)&gb[8];
            if (SPLIT) {
                const unsigned short* la = Alo + arow + k0;
                const unsigned short* lb = Blo + brow + k0;
                *(float4*)&AsL[srow * LDK + scol]     = *(const float4*)&la[0];
                *(float4*)&AsL[srow * LDK + scol + 8] = *(const float4*)&la[8];
                *(float4*)&BsL[srow * LDK + scol]     = *(const float4*)&lb[0];
                *(float4*)&BsL[srow * LDK + scol + 8] = *(const float4*)&lb[8];
            }
        }
        __syncthreads();

        short8 ah[4], bh[4], al[4], bl[4];
#pragma unroll
        for (int i = 0; i < 4; ++i) {
            ah[i] = *(const short8*)&AsH[(wm + i * 16 + l15) * LDK + quad * 8];
            bh[i] = *(const short8*)&BsH[(wn + i * 16 + l15) * LDK + quad * 8];
            if (SPLIT) {
                al[i] = *(const short8*)&AsL[(wm + i * 16 + l15) * LDK + quad * 8];
                bl[i] = *(const short8*)&BsL[(wn + i * 16 + l15) * LDK + quad * 8];
            }
        }
#pragma unroll
        for (int i = 0; i < 4; ++i)
#pragma unroll
            for (int j = 0; j < 4; ++j) {
                acc[i][j] = __builtin_amdgcn_mfma_f32_16x16x32_bf16(ah[i], bh[j], acc[i][j], 0, 0, 0);
                if (SPLIT) {
                    acc[i][j] = __builtin_amdgcn_mfma_f32_16x16x32_bf16(ah[i], bl[j], acc[i][j], 0, 0, 0);
                    acc[i][j] = __builtin_amdgcn_mfma_f32_16x16x32_bf16(al[i], bh[j], acc[i][j], 0, 0, 0);
                }
            }
        __syncthreads();
    }

    // C/D layout: col = lane&15, row = quad*4 + reg
#pragma unroll
    for (int i = 0; i < 4; ++i)
#pragma unroll
        for (int j = 0; j < 4; ++j) {
            const int m = m0 + wm + i * 16 + quad * 4;
            const int n = n0 + wn + j * 16 + l15;
#pragma unroll
            for (int r = 0; r < 4; ++r) {
                const float v = acc[i][j][r];
                const long idx = (long)(m + r) * ldc + n;
                if (OUTMODE == 0) {
                    Cf[idx] = v;
                } else if (OUTMODE == 1) {
                    Ch[idx] = f2bf(v);
                } else {
                    const unsigned short hi = f2bf(v);
                    Ch[idx] = hi;
                    Cl[idx] = f2bf(v - bf2f(hi));
                }
            }
        }
}

// ---------------- softmax: fp32 chunk row -> bf16 full-f row ----------------
__global__ __launch_bounds__(256) void softmax_bf(
    const float* __restrict__ fin, unsigned short* __restrict__ fout,
    int N, int rowsPerBatch, int noff)
{
    const int b = blockIdx.x / rowsPerBatch;
    const int nc = blockIdx.x % rowsPerBatch;
    const float* p = fin + (long)blockIdx.x * N;
    unsigned short* q = fout + ((long)b * N + noff + nc) * N;
    const int tid = threadIdx.x;
    float v[8];
    float mx = -1e30f;
#pragma unroll
    for (int i = 0; i < 8; ++i) {
        v[i] = p[tid + i * 256];
        mx = fmaxf(mx, v[i]);
    }
    __shared__ float red[256];
    red[tid] = mx;
    __syncthreads();
    for (int s = 128; s > 0; s >>= 1) {
        if (tid < s) red[tid] = fmaxf(red[tid], red[tid + s]);
        __syncthreads();
    }
    mx = red[0];
    __syncthreads();
    float sum = 0.f;
#pragma unroll
    for (int i = 0; i < 8; ++i) {
        v[i] = __expf(v[i] - mx);
        sum += v[i];
    }
    red[tid] = sum;
    __syncthreads();
    for (int s = 128; s > 0; s >>= 1) {
        if (tid < s) red[tid] += red[tid + s];
        __syncthreads();
    }
    const float inv = 1.0f / red[0];
#pragma unroll
    for (int i = 0; i < 8; ++i) q[tid + i * 256] = f2bf(v[i] * inv);
}

// ---------------- BatchNorm ----------------
__global__ __launch_bounds__(256) void bn_stats(
    const float* __restrict__ z, float* __restrict__ mean, float* __restrict__ rstd,
    int B, int C, int N)
{
    const int c = blockIdx.x;
    const int tid = threadIdx.x;
    float s = 0.f, sq = 0.f;
    for (int b = 0; b < B; ++b) {
        const float* p = z + ((long)b * C + c) * N;
        for (int i = tid * 4; i < N; i += 1024) {
            const float4 v = *(const float4*)&p[i];
            s += v.x + v.y + v.z + v.w;
            sq += v.x * v.x + v.y * v.y + v.z * v.z + v.w * v.w;
        }
    }
    __shared__ float rs[256], rq[256];
    rs[tid] = s;
    rq[tid] = sq;
    __syncthreads();
    for (int st = 128; st > 0; st >>= 1) {
        if (tid < st) { rs[tid] += rs[tid + st]; rq[tid] += rq[tid + st]; }
        __syncthreads();
    }
    if (tid == 0) {
        const float cnt = (float)B * (float)N;
        const float m = rs[0] / cnt;
        const float var = rq[0] / cnt - m * m;
        mean[c] = m;
        rstd[c] = rsqrtf(var + 1e-5f);
    }
}

__global__ __launch_bounds__(256) void bn_apply(
    const float* __restrict__ z, const float* __restrict__ x,
    const float* __restrict__ mean, const float* __restrict__ rstd,
    const float* __restrict__ gamma, const float* __restrict__ beta,
    float* __restrict__ out, int C, int N)
{
    const long i = ((long)blockIdx.x * 256 + threadIdx.x) * 4;
    const int c = (int)((i / N) % C);
    const float mu = mean[c], rs = rstd[c], ga = gamma[c], be = beta[c];
    const float4 zv = *(const float4*)&z[i];
    const float4 xv = *(const float4*)&x[i];
    float4 o;
    o.x = (zv.x - mu) * rs * ga + be + xv.x;
    o.y = (zv.y - mu) * rs * ga + be + xv.y;
    o.z = (zv.z - mu) * rs * ga + be + xv.z;
    o.w = (zv.w - mu) * rs * ga + be + xv.w;
    *(float4*)&out[i] = o;
}

extern "C" void kernel_launch(void* const* d_in, const int* in_sizes, int n_in,
                              void* d_out, int out_size, void* d_ws, size_t ws_size,
                              hipStream_t stream)
{
    const int B = 8, C = 512, N = 2048, P = 256;
    const int NC = 512;                       // f row-chunk
    const float* x      = (const float*)d_in[0];
    const float* Wg     = (const float*)d_in[1];
    const float* Wtheta = (const float*)d_in[2];
    const float* Wphi   = (const float*)d_in[3];
    const float* Wz     = (const float*)d_in[4];
    const float* gamma  = (const float*)d_in[5];
    const float* beta   = (const float*)d_in[6];
    float* out = (float*)d_out;

    // ---- workspace layout (float units) ----
    float* ws = (float*)d_ws;
    const long NCle = (long)N * C;            // 1,048,576 per batch
    const long NP   = (long)N * P;            // 524,288 per batch
    const long R0   = (long)B * NCle;         // 8.39M floats (xt hi+lo / f32c / z)
    unsigned short* xtH  = (unsigned short*)ws;                 // B*N*C
    unsigned short* xtL  = xtH + B * NCle;
    float*          f32c = ws;                                  // aliases xt (dead after g)
    float*          z    = ws;                                  // aliases f32c (dead after softmax)
    unsigned short* thH  = (unsigned short*)(ws + R0);          // B*N*P each
    unsigned short* thL  = thH + B * NP;
    unsigned short* phH  = thL + B * NP;
    unsigned short* phL  = phH + B * NP;
    unsigned short* gbf  = (unsigned short*)(ws + R0 + 4 * (B * NP / 2));  // B*P*N
    unsigned short* fbf  = gbf + B * NP;                        // B*N*N
    unsigned short* ybf  = fbf + (long)B * N * N;               // B*N*P
    unsigned short* WthH = ybf + B * NP;                        // P*C each
    unsigned short* WthL = WthH + (long)P * C;
    unsigned short* WphH = WthL + (long)P * C;
    unsigned short* WphL = WphH + (long)P * C;
    unsigned short* WgB  = WphL + (long)P * C;
    unsigned short* WzB  = WgB + (long)P * C;
    float*          mean = (float*)thH;                         // dead after scores
    float*          rstd = mean + C;

    const long sX = (long)C * N;

    // 1: transpose+split x -> xT hi/lo [B][N][C]
    transpose_split<<<dim3(N / 32, C / 32, B), 256, 0, stream>>>(x, xtH, xtL, C, N);
    // 2: weight preps
    split_w<<<(P * C + 255) / 256, 256, 0, stream>>>(Wtheta, WthH, WthL, P * C);
    split_w<<<(P * C + 255) / 256, 256, 0, stream>>>(Wphi, WphH, WphL, P * C);
    cast_bf16<<<P * C / 1024, 256, 0, stream>>>(Wg, WgB);
    cast_bf16<<<P * C / 1024, 256, 0, stream>>>(Wz, WzB);

    // 3: thT [B][N][P] = xT @ Wth^T (split in, split out)
    mfma_gemm<true, 2><<<dim3(P / MT, N / MT, B), 256, 0, stream>>>(
        xtH, xtL, WthH, WthL, thH, thL, N, P, C, C, C, P, NCle, 0, NP);
    // 4: phT [B][N][P]
    mfma_gemm<true, 2><<<dim3(P / MT, N / MT, B), 256, 0, stream>>>(
        xtH, xtL, WphH, WphL, phH, phL, N, P, C, C, C, P, NCle, 0, NP);
    // 5: g [B][P][N] = Wg @ xT^T (plain, bf16 out)
    mfma_gemm<false, 1><<<dim3(N / MT, P / MT, B), 256, 0, stream>>>(
        WgB, WgB, xtH, xtH, gbf, gbf, P, N, C, C, C, N, 0, NCle, NP);

    // 6: scores (split) + softmax, chunked over rows (f32c aliases xt: xt dead now)
    for (int c = 0; c < N / NC; ++c) {
        mfma_gemm<true, 0><<<dim3(N / MT, NC / MT, B), 256, 0, stream>>>(
            thH + (long)c * NC * P, thL + (long)c * NC * P, phH, phL, f32c, f32c,
            NC, N, P, P, P, N, NP, NP, (long)NC * N);
        softmax_bf<<<B * NC, 256, 0, stream>>>(f32c, fbf, N, NC, c * NC);
    }

    // 7: yT [B][N][P] = fbf @ g^T (plain, bf16 out)
    mfma_gemm<false, 1><<<dim3(P / MT, N / MT, B), 256, 0, stream>>>(
        fbf, fbf, gbf, gbf, ybf, ybf, N, P, N, N, N, P, (long)N * N, NP, NP);

    // 8: z [B][C][N] = Wz @ yT^T (plain, fp32 out; z aliases f32c, dead now)
    mfma_gemm<false, 0><<<dim3(N / MT, C / MT, B), 256, 0, stream>>>(
        WzB, WzB, ybf, ybf, z, z, C, N, P, P, P, N, 0, NP, sX);

    // 9: BN + residual
    bn_stats<<<C, 256, 0, stream>>>(z, mean, rstd, B, C, N);
    bn_apply<<<(int)((B * sX) / 1024), 256, 0, stream>>>(z, x, mean, rstd, gamma, beta, out, C, N);
}

// Round 4
// 379.425 us; speedup vs baseline: 2.3542x; 1.0504x over previous
//
#include <hip/hip_runtime.h>
#include <hip/hip_bf16.h>

// B=8, C=512, N=2048, P=256.
// Round 4: m97-style GEMM engine — global_load_lds(16B) async staging into
// unpadded LDS, parameterized wave tiles so every GEMM gets >=512 blocks.
//   theta/phi/scores: split-bf16 (hi/lo, 3 MFMAs) -> fp32-class logits
//   g, y, z:          plain bf16 (post-softmax, not exp-amplified)
// Layouts (all MFMA operands K-contiguous):
//   xT[h/l] [B][N][C], thT/phT [B][N][P] (hi/lo), g [B][P][N] bf16,
//   f chunked fp32 -> softmax -> fbf [B][N][N] bf16, yT [B][N][P] bf16,
//   z [B][C][N] fp32, BN+residual -> out.

typedef __attribute__((ext_vector_type(8))) short short8;
typedef __attribute__((ext_vector_type(4))) float floatx4;

#define AS1 __attribute__((address_space(1)))
#define AS3 __attribute__((address_space(3)))

__device__ __forceinline__ void stage16(const unsigned short* gp, unsigned short* lp) {
    // LDS dest is wave-uniform base + lane*16; gp is per-lane.
    __builtin_amdgcn_global_load_lds((const AS1 void*)gp, (AS3 void*)lp, 16, 0, 0);
}

// ---------------- bf16 helpers ----------------
__device__ __forceinline__ unsigned short f2bf(float v) {
    __hip_bfloat16 h = __float2bfloat16(v);
    return *(unsigned short*)&h;
}
__device__ __forceinline__ float bf2f(unsigned short u) {
    __hip_bfloat16 h;
    *(unsigned short*)&h = u;
    return __bfloat162float(h);
}

// transpose + hi/lo split: X [R][N] fp32 -> Thi/Tlo [N][R] bf16 (batched over z)
__global__ __launch_bounds__(256) void transpose_split(
    const float* __restrict__ X, unsigned short* __restrict__ Thi,
    unsigned short* __restrict__ Tlo, int R, int N)
{
    X   += (long)blockIdx.z * R * N;
    Thi += (long)blockIdx.z * N * R;
    Tlo += (long)blockIdx.z * N * R;
    __shared__ float s[32][33];
    const int tx = threadIdx.x & 31, ty = threadIdx.x >> 5;
    const int n0 = blockIdx.x * 32, r0 = blockIdx.y * 32;
#pragma unroll
    for (int r = 0; r < 4; ++r)
        s[ty + r * 8][tx] = X[(long)(r0 + ty + r * 8) * N + n0 + tx];
    __syncthreads();
#pragma unroll
    for (int r = 0; r < 4; ++r) {
        const int n = ty + r * 8;
        const float v = s[tx][n];
        const unsigned short hi = f2bf(v);
        const unsigned short lo = f2bf(v - bf2f(hi));
        Thi[(long)(n0 + n) * R + r0 + tx] = hi;
        Tlo[(long)(n0 + n) * R + r0 + tx] = lo;
    }
}

__global__ __launch_bounds__(256) void split_w(
    const float* __restrict__ W, unsigned short* __restrict__ Whi,
    unsigned short* __restrict__ Wlo, int n)
{
    const int i = blockIdx.x * 256 + threadIdx.x;
    if (i < n) {
        const float v = W[i];
        const unsigned short hi = f2bf(v);
        Whi[i] = hi;
        Wlo[i] = f2bf(v - bf2f(hi));
    }
}

__global__ __launch_bounds__(256) void cast_bf16(
    const float* __restrict__ X, unsigned short* __restrict__ Y)
{
    const long i = ((long)blockIdx.x * 256 + threadIdx.x) * 4;
    const float4 v = *(const float4*)&X[i];
    ushort4 o;
    o.x = f2bf(v.x); o.y = f2bf(v.y); o.z = f2bf(v.z); o.w = f2bf(v.w);
    *(ushort4*)&Y[i] = o;
}

// ---------------- MFMA GEMM (m97-style) ----------------
// C[M][N] = A[M][K] * B[N][K]^T, bf16 K-contiguous inputs, fp32 accum.
// Tile: MTM x MTN = (FM*32) x (FN*32); 4 waves in 2x2; wave tile 16FM x 16FN.
// SPLIT: C = Ah*Bh + Ah*Bl + Al*Bh.
// OUTMODE: 0 = fp32, 1 = bf16, 2 = hi/lo split bf16.
#define BK 32

template <bool SPLIT, int OUTMODE, int FM, int FN>
__global__ __launch_bounds__(256) void mfma_gemm(
    const unsigned short* __restrict__ Ahi, const unsigned short* __restrict__ Alo,
    const unsigned short* __restrict__ Bhi, const unsigned short* __restrict__ Blo,
    void* __restrict__ Cout, void* __restrict__ Cout2,
    int K, int lda, int ldb, int ldc,
    long sA, long sB, long sC)
{
    constexpr int MTM = FM * 32, MTN = FN * 32;
    constexpr int nIA = MTM / 16, nIB = MTN / 16;   // 1KB-chunk instructions

    Ahi += (long)blockIdx.z * sA;
    Bhi += (long)blockIdx.z * sB;
    if (SPLIT) { Alo += (long)blockIdx.z * sA; Blo += (long)blockIdx.z * sB; }
    float* Cf = (float*)Cout + (long)blockIdx.z * sC;
    unsigned short* Ch = (unsigned short*)Cout + (long)blockIdx.z * sC;
    unsigned short* Cl = (unsigned short*)Cout2 + (long)blockIdx.z * sC;

    __shared__ unsigned short AsH[MTM * BK], BsH[MTN * BK];
    __shared__ unsigned short AsL[SPLIT ? MTM * BK : 8], BsL[SPLIT ? MTN * BK : 8];

    const int tid = threadIdx.x;
    const int wid = tid >> 6, lane = tid & 63;
    const int wm = (wid >> 1) * (FM * 16), wn = (wid & 1) * (FN * 16);
    const int l15 = lane & 15, quad = lane >> 4;
    const int m0 = blockIdx.y * MTM, n0 = blockIdx.x * MTN;

    // staging lane mapping: lane -> (row = lane>>2 within 16-row group, col8)
    const int srow = lane >> 2;
    const int scol = (lane & 3) * 8;

    floatx4 acc[FM][FN];
#pragma unroll
    for (int i = 0; i < FM; ++i)
#pragma unroll
        for (int j = 0; j < FN; ++j) acc[i][j] = (floatx4){0.f, 0.f, 0.f, 0.f};

    for (int k0 = 0; k0 < K; k0 += BK) {
        // async stage A tile rows [m0, m0+MTM), 32 k each
#pragma unroll
        for (int j = wid; j < nIA; j += 4) {
            const long off = (long)(m0 + j * 16 + srow) * lda + k0 + scol;
            stage16(Ahi + off, &AsH[j * 512]);
            if (SPLIT) stage16(Alo + off, &AsL[j * 512]);
        }
#pragma unroll
        for (int j = wid; j < nIB; j += 4) {
            const long off = (long)(n0 + j * 16 + srow) * ldb + k0 + scol;
            stage16(Bhi + off, &BsH[j * 512]);
            if (SPLIT) stage16(Blo + off, &BsL[j * 512]);
        }
        __syncthreads();   // drains vmcnt (global_load_lds) + lgkm

        short8 ah[FM], bh[FN], al[SPLIT ? FM : 1], bl[SPLIT ? FN : 1];
#pragma unroll
        for (int i = 0; i < FM; ++i) {
            ah[i] = *(const short8*)&AsH[(wm + i * 16 + l15) * BK + quad * 8];
            if (SPLIT) al[i] = *(const short8*)&AsL[(wm + i * 16 + l15) * BK + quad * 8];
        }
#pragma unroll
        for (int j = 0; j < FN; ++j) {
            bh[j] = *(const short8*)&BsH[(wn + j * 16 + l15) * BK + quad * 8];
            if (SPLIT) bl[j] = *(const short8*)&BsL[(wn + j * 16 + l15) * BK + quad * 8];
        }
#pragma unroll
        for (int i = 0; i < FM; ++i)
#pragma unroll
            for (int j = 0; j < FN; ++j) {
                acc[i][j] = __builtin_amdgcn_mfma_f32_16x16x32_bf16(ah[i], bh[j], acc[i][j], 0, 0, 0);
                if (SPLIT) {
                    acc[i][j] = __builtin_amdgcn_mfma_f32_16x16x32_bf16(ah[i], bl[j], acc[i][j], 0, 0, 0);
                    acc[i][j] = __builtin_amdgcn_mfma_f32_16x16x32_bf16(al[i], bh[j], acc[i][j], 0, 0, 0);
                }
            }
        __syncthreads();
    }

    // C/D layout: col = lane&15, row = quad*4 + reg
#pragma unroll
    for (int i = 0; i < FM; ++i)
#pragma unroll
        for (int j = 0; j < FN; ++j) {
            const int m = m0 + wm + i * 16 + quad * 4;
            const int n = n0 + wn + j * 16 + l15;
#pragma unroll
            for (int r = 0; r < 4; ++r) {
                const float v = acc[i][j][r];
                const long idx = (long)(m + r) * ldc + n;
                if (OUTMODE == 0) {
                    Cf[idx] = v;
                } else if (OUTMODE == 1) {
                    Ch[idx] = f2bf(v);
                } else {
                    const unsigned short hi = f2bf(v);
                    Ch[idx] = hi;
                    Cl[idx] = f2bf(v - bf2f(hi));
                }
            }
        }
}

// ---------------- softmax: fp32 chunk row -> bf16 full-f row ----------------
__global__ __launch_bounds__(256) void softmax_bf(
    const float* __restrict__ fin, unsigned short* __restrict__ fout,
    int N, int rowsPerBatch, int noff)
{
    const int b = blockIdx.x / rowsPerBatch;
    const int nc = blockIdx.x % rowsPerBatch;
    const float* p = fin + (long)blockIdx.x * N;
    unsigned short* q = fout + ((long)b * N + noff + nc) * N;
    const int tid = threadIdx.x;
    float v[8];
    float mx = -1e30f;
#pragma unroll
    for (int i = 0; i < 8; ++i) {
        v[i] = p[tid + i * 256];
        mx = fmaxf(mx, v[i]);
    }
    __shared__ float red[256];
    red[tid] = mx;
    __syncthreads();
    for (int s = 128; s > 0; s >>= 1) {
        if (tid < s) red[tid] = fmaxf(red[tid], red[tid + s]);
        __syncthreads();
    }
    mx = red[0];
    __syncthreads();
    float sum = 0.f;
#pragma unroll
    for (int i = 0; i < 8; ++i) {
        v[i] = __expf(v[i] - mx);
        sum += v[i];
    }
    red[tid] = sum;
    __syncthreads();
    for (int s = 128; s > 0; s >>= 1) {
        if (tid < s) red[tid] += red[tid + s];
        __syncthreads();
    }
    const float inv = 1.0f / red[0];
#pragma unroll
    for (int i = 0; i < 8; ++i) q[tid + i * 256] = f2bf(v[i] * inv);
}

// ---------------- BatchNorm ----------------
__global__ __launch_bounds__(256) void bn_stats(
    const float* __restrict__ z, float* __restrict__ mean, float* __restrict__ rstd,
    int B, int C, int N)
{
    const int c = blockIdx.x;
    const int tid = threadIdx.x;
    float s = 0.f, sq = 0.f;
    for (int b = 0; b < B; ++b) {
        const float* p = z + ((long)b * C + c) * N;
        for (int i = tid * 4; i < N; i += 1024) {
            const float4 v = *(const float4*)&p[i];
            s += v.x + v.y + v.z + v.w;
            sq += v.x * v.x + v.y * v.y + v.z * v.z + v.w * v.w;
        }
    }
    __shared__ float rs[256], rq[256];
    rs[tid] = s;
    rq[tid] = sq;
    __syncthreads();
    for (int st = 128; st > 0; st >>= 1) {
        if (tid < st) { rs[tid] += rs[tid + st]; rq[tid] += rq[tid + st]; }
        __syncthreads();
    }
    if (tid == 0) {
        const float cnt = (float)B * (float)N;
        const float m = rs[0] / cnt;
        const float var = rq[0] / cnt - m * m;
        mean[c] = m;
        rstd[c] = rsqrtf(var + 1e-5f);
    }
}

__global__ __launch_bounds__(256) void bn_apply(
    const float* __restrict__ z, const float* __restrict__ x,
    const float* __restrict__ mean, const float* __restrict__ rstd,
    const float* __restrict__ gamma, const float* __restrict__ beta,
    float* __restrict__ out, int C, int N)
{
    const long i = ((long)blockIdx.x * 256 + threadIdx.x) * 4;
    const int c = (int)((i / N) % C);
    const float mu = mean[c], rs = rstd[c], ga = gamma[c], be = beta[c];
    const float4 zv = *(const float4*)&z[i];
    const float4 xv = *(const float4*)&x[i];
    float4 o;
    o.x = (zv.x - mu) * rs * ga + be + xv.x;
    o.y = (zv.y - mu) * rs * ga + be + xv.y;
    o.z = (zv.z - mu) * rs * ga + be + xv.z;
    o.w = (zv.w - mu) * rs * ga + be + xv.w;
    *(float4*)&out[i] = o;
}

extern "C" void kernel_launch(void* const* d_in, const int* in_sizes, int n_in,
                              void* d_out, int out_size, void* d_ws, size_t ws_size,
                              hipStream_t stream)
{
    const int B = 8, C = 512, N = 2048, P = 256;
    const int NC = 512;                       // f row-chunk
    const float* x      = (const float*)d_in[0];
    const float* Wg     = (const float*)d_in[1];
    const float* Wtheta = (const float*)d_in[2];
    const float* Wphi   = (const float*)d_in[3];
    const float* Wz     = (const float*)d_in[4];
    const float* gamma  = (const float*)d_in[5];
    const float* beta   = (const float*)d_in[6];
    float* out = (float*)d_out;

    // ---- workspace layout (float units) ----
    float* ws = (float*)d_ws;
    const long NCle = (long)N * C;            // 1,048,576 per batch
    const long NP   = (long)N * P;            // 524,288 per batch
    const long R0   = (long)B * NCle;         // 8.39M floats
    unsigned short* xtH  = (unsigned short*)ws;                 // B*N*C
    unsigned short* xtL  = xtH + B * NCle;
    float*          f32c = ws;                                  // aliases xt (dead after g)
    float*          z    = ws;                                  // aliases f32c
    unsigned short* thH  = (unsigned short*)(ws + R0);          // B*N*P each
    unsigned short* thL  = thH + B * NP;
    unsigned short* phH  = thL + B * NP;
    unsigned short* phL  = phH + B * NP;
    unsigned short* gbf  = (unsigned short*)(ws + R0 + 4 * (B * NP / 2));  // B*P*N
    unsigned short* fbf  = gbf + B * NP;                        // B*N*N
    unsigned short* ybf  = fbf + (long)B * N * N;               // B*N*P
    unsigned short* WthH = ybf + B * NP;                        // P*C each
    unsigned short* WthL = WthH + (long)P * C;
    unsigned short* WphH = WthL + (long)P * C;
    unsigned short* WphL = WphH + (long)P * C;
    unsigned short* WgB  = WphL + (long)P * C;
    unsigned short* WzB  = WgB + (long)P * C;
    float*          mean = (float*)thH;                         // dead after scores
    float*          rstd = mean + C;

    const long sX = (long)C * N;

    // 1: transpose+split x -> xT hi/lo [B][N][C]
    transpose_split<<<dim3(N / 32, C / 32, B), 256, 0, stream>>>(x, xtH, xtL, C, N);
    // 2: weight preps
    split_w<<<(P * C + 255) / 256, 256, 0, stream>>>(Wtheta, WthH, WthL, P * C);
    split_w<<<(P * C + 255) / 256, 256, 0, stream>>>(Wphi, WphH, WphL, P * C);
    cast_bf16<<<P * C / 1024, 256, 0, stream>>>(Wg, WgB);
    cast_bf16<<<P * C / 1024, 256, 0, stream>>>(Wz, WzB);

    // 3: thT [B][N][P] = xT @ Wth^T (split, split-out); tiles 128x64 -> 512 blocks
    mfma_gemm<true, 2, 4, 2><<<dim3(P / 64, N / 128, B), 256, 0, stream>>>(
        xtH, xtL, WthH, WthL, thH, thL, C, C, C, P, NCle, 0, NP);
    // 4: phT
    mfma_gemm<true, 2, 4, 2><<<dim3(P / 64, N / 128, B), 256, 0, stream>>>(
        xtH, xtL, WphH, WphL, phH, phL, C, C, C, P, NCle, 0, NP);
    // 5: g [B][P][N] = Wg @ xT^T (plain, bf16 out); tiles 64x128 -> 512 blocks
    mfma_gemm<false, 1, 2, 4><<<dim3(N / 128, P / 64, B), 256, 0, stream>>>(
        WgB, WgB, xtH, xtH, gbf, gbf, C, C, C, N, 0, NCle, NP);

    // 6: scores (split) + softmax, chunked (f32c aliases xt: xt dead now)
    for (int c = 0; c < N / NC; ++c) {
        mfma_gemm<true, 0, 4, 4><<<dim3(N / 128, NC / 128, B), 256, 0, stream>>>(
            thH + (long)c * NC * P, thL + (long)c * NC * P, phH, phL, f32c, f32c,
            P, P, P, N, NP, NP, (long)NC * N);
        softmax_bf<<<B * NC, 256, 0, stream>>>(f32c, fbf, N, NC, c * NC);
    }

    // 7: yT [B][N][P] = fbf @ g^T (plain, bf16 out); tiles 128x64 -> 512 blocks
    mfma_gemm<false, 1, 4, 2><<<dim3(P / 64, N / 128, B), 256, 0, stream>>>(
        fbf, fbf, gbf, gbf, ybf, ybf, N, N, N, P, (long)N * N, NP, NP);

    // 8: z [B][C][N] = Wz @ yT^T (plain, fp32 out; aliases f32c)
    mfma_gemm<false, 0, 4, 4><<<dim3(N / 128, C / 128, B), 256, 0, stream>>>(
        WzB, WzB, ybf, ybf, z, z, P, P, P, N, 0, NP, sX);

    // 9: BN + residual
    bn_stats<<<C, 256, 0, stream>>>(z, mean, rstd, B, C, N);
    bn_apply<<<(int)((B * sX) / 1024), 256, 0, stream>>>(z, x, mean, rstd, gamma, beta, out, C, N);
}